// Round 12
// baseline (162.613 us; speedup 1.0000x reference)
//
#include <hip/hip_runtime.h>
#include <hip/hip_bf16.h>

// MPNNConv (champion R4/R10 dataflow, launch-fused, race-fixed):
//   s[n] = h[n] @ W1[0:128] + b1 (f32 swz), g[n] = h[n] @ W1[128:256] (bf16 swz, L2-resident)
//   Hsum[n] = sum_{e: rows[e]=n} relu(s[n] + g[cols[e]] + ef[e] @ W1e)   (K=32 MFMA)
//   out[n]  = Hsum[n] @ W2 + deg[n]*b2     (fused into layer1 via LDS + per-col GEMV)
// CSR on-device; ef permuted into CSR order as bf16 (efb: 64B full-line records).
// NOTE: counts is zeroed by hipMemsetAsync BEFORE prep_hist (same stream) --
// zeroing inside the same launch as the atomics is a cross-block race (R11 abort).

typedef __attribute__((ext_vector_type(8))) short bf16x8;
typedef __attribute__((ext_vector_type(4))) float f32x4;

#define ND 128
#define ED 32

__device__ __forceinline__ short f2bf(float x) {
  unsigned int u = __float_as_uint(x);
  unsigned int r = (u + 0x7FFFu + ((u >> 16) & 1u)) >> 16;
  return (short)r;
}

__device__ __forceinline__ float bf2f(short s) {
  return __uint_as_float(((unsigned int)(unsigned short)s) << 16);
}

__device__ __forceinline__ f32x4 bf8lo(bf16x8 v) {
  f32x4 r;
  #pragma unroll
  for (int j = 0; j < 4; ++j) r[j] = bf2f(v[j]);
  return r;
}
__device__ __forceinline__ f32x4 bf8hi(bf16x8 v) {
  f32x4 r;
  #pragma unroll
  for (int j = 0; j < 4; ++j) r[j] = bf2f(v[4 + j]);
  return r;
}

// swizzled offset within a 128-wide row for col c (c = ct*16 + cc):
// o = (ct>>2)*64 + (cc>>2)*16 + (ct&3)*4 + (cc&3)
__device__ __forceinline__ int swz(int c) {
  int ct = c >> 4, cc = c & 15;
  return (ct >> 2) * 64 + (cc >> 2) * 16 + (ct & 3) * 4 + (cc & 3);
}

// --- fused: weight pre-layouts (blocks [0,128)) | hist/rank/rc (rest) ---
__global__ __launch_bounds__(256) void prep_hist_kernel(
    const float* __restrict__ W1, const float* __restrict__ W2,
    const void* __restrict__ ei, int* __restrict__ counts,
    int* __restrict__ rank, unsigned int* __restrict__ rc,
    short* __restrict__ w12t, short* __restrict__ w1eA, short* __restrict__ w2t,
    int E) {
  int b = blockIdx.x;
  if (b < 128) {
    int t = b * 256 + threadIdx.x;
    if (t < 256 * 128) {  // w12t[n'][k]: n'<128 -> W1[k][n'] ; else W1[128+k][n'-128]
      int np = t >> 7, k = t & 127;
      float v = (np < 128) ? W1[k * 128 + np] : W1[(128 + k) * 128 + (np - 128)];
      w12t[t] = f2bf(v);
    }
    if (t < 128 * 128) {  // w2t[n][k] = W2[k][n]  (row n = W2 column n, GEMV-contiguous)
      int n = t >> 7, k = t & 127;
      w2t[t] = f2bf(W2[k * 128 + n]);
    }
    if (t < 8 * 64 * 8) { // w1eA[ct][lane][j] = W1[256+lg*8+j][ct*16+li]
      int ct = t >> 9, lane = (t >> 3) & 63, j = t & 7;
      int li = lane & 15, lg = lane >> 4;
      w1eA[t] = f2bf(W1[(256 + lg * 8 + j) * 128 + ct * 16 + li]);
    }
  } else {
    int e = (b - 128) * 256 + threadIdx.x;
    if (e < E) {
      const unsigned int* u = (const unsigned int*)ei;
      int is64 = 1;
      #pragma unroll
      for (int i = 0; i < 16; ++i)
        if (u[2 * i + 1] != 0u) is64 = 0;   // uniform addresses -> scalar loads
      int r, c;
      if (is64) {
        r = (int)((const long long*)ei)[e];
        c = (int)((const long long*)ei)[(long long)E + e];
      } else {
        r = ((const int*)ei)[e];
        c = ((const int*)ei)[E + e];
      }
      rank[e] = atomicAdd(&counts[r], 1);
      rc[e] = ((unsigned int)r << 16) | (unsigned int)c;   // N < 65536
    }
  }
}

// --- single-block scan: 1024 threads x 16 elems ---
__global__ __launch_bounds__(1024) void scan_kernel(const int* __restrict__ counts,
                                                    int* __restrict__ row_ptr, int n) {
  __shared__ int wtot[16];
  int tid = threadIdx.x;
  int lane = tid & 63, w = tid >> 6;
  int base_i = tid * 16;
  int c[16];
  int tot = 0;
  #pragma unroll
  for (int j = 0; j < 16; ++j) {
    int i = base_i + j;
    c[j] = (i < n) ? counts[i] : 0;
    tot += c[j];
  }
  int x = tot;
  #pragma unroll
  for (int d = 1; d < 64; d <<= 1) {
    int t = __shfl_up(x, d);
    if (lane >= d) x += t;
  }
  if (lane == 63) wtot[w] = x;
  __syncthreads();
  if (w == 0) {
    int y = (lane < 16) ? wtot[lane] : 0;
    #pragma unroll
    for (int d = 1; d < 16; d <<= 1) {
      int t = __shfl_up(y, d);
      if (lane >= d) y += t;
    }
    if (lane < 16) wtot[lane] = y;
  }
  __syncthreads();
  int waveoff = (w == 0) ? 0 : wtot[w - 1];
  int run = waveoff + x - tot;  // exclusive prefix
  if (tid == 0) row_ptr[0] = 0;
  #pragma unroll
  for (int j = 0; j < 16; ++j) {
    int i = base_i + j;
    if (i < n) {
      run += c[j];
      row_ptr[i + 1] = run;
    }
  }
}

// --- fused: sg GEMM (blocks [0,SGB)) + ef->efb bf16 permute (rest) ---
__global__ __launch_bounds__(256, 4) void scatter_sg_kernel(
    const float* __restrict__ ef, const int* __restrict__ row_ptr,
    const int* __restrict__ rank, const unsigned int* __restrict__ rc,
    const float* __restrict__ h, const short* __restrict__ w12t,
    const float* __restrict__ b1, short* __restrict__ efb,
    int* __restrict__ ccol, float* __restrict__ s2, short* __restrict__ g2,
    int N, int E) {
  int b = blockIdx.x;
  int SGB = (N + 63) >> 6;
  if (b < SGB) {
    // ---- s = h@W1top + b1 (f32 swz), g = h@W1mid (bf16 swz)
    int lane = threadIdx.x & 63, w = threadIdx.x >> 6;
    int li = lane & 15, lg = lane >> 4;
    int base = b * 64 + w * 16;
    int rowm = base + li;
    if (rowm >= N) rowm = N - 1;
    float breg[8];
    #pragma unroll
    for (int nt = 0; nt < 8; ++nt) breg[nt] = b1[nt * 16 + li];
    f32x4 acc[16];
    #pragma unroll
    for (int nt = 0; nt < 16; ++nt) acc[nt] = (f32x4){0.f, 0.f, 0.f, 0.f};
    #pragma unroll
    for (int kc = 0; kc < 4; ++kc) {
      f32x4 f0 = *(const f32x4*)(h + (size_t)rowm * ND + kc * 32 + lg * 8);
      f32x4 f1 = *(const f32x4*)(h + (size_t)rowm * ND + kc * 32 + lg * 8 + 4);
      bf16x8 a;
      #pragma unroll
      for (int j = 0; j < 4; ++j) { a[j] = f2bf(f0[j]); a[4 + j] = f2bf(f1[j]); }
      #pragma unroll
      for (int nt = 0; nt < 16; ++nt) {
        bf16x8 bb = *(const bf16x8*)(w12t + (nt * 16 + li) * 128 + kc * 32 + lg * 8);
        acc[nt] = __builtin_amdgcn_mfma_f32_16x16x32_bf16(a, bb, acc[nt], 0, 0, 0);
      }
    }
    #pragma unroll
    for (int nt = 0; nt < 16; ++nt)
      #pragma unroll
      for (int r = 0; r < 4; ++r) {
        int row = base + lg * 4 + r;
        if (row < N) {
          if (nt < 8) {
            s2[(size_t)row * 128 + swz(nt * 16 + li)] = acc[nt][r] + breg[nt];
          } else {
            g2[(size_t)row * 128 + swz((nt - 8) * 16 + li)] = f2bf(acc[nt][r]);
          }
        }
      }
  } else {
    // ---- permute: 4 threads/edge; coalesced ef read, full-line scattered write
    int gt = (b - SGB) * 256 + threadIdx.x;
    int e = gt >> 2, part = gt & 3;
    if (e < E) {
      unsigned int p = rc[e];
      int r = (int)(p >> 16), c = (int)(p & 0xffffu);
      int pos = row_ptr[r] + rank[e];
      f32x4 a0 = *(const f32x4*)(ef + (size_t)e * ED + part * 8);
      f32x4 a1 = *(const f32x4*)(ef + (size_t)e * ED + part * 8 + 4);
      bf16x8 ob;
      #pragma unroll
      for (int j = 0; j < 4; ++j) { ob[j] = f2bf(a0[j]); ob[4 + j] = f2bf(a1[j]); }
      *(bf16x8*)(efb + (size_t)pos * ED + part * 8) = ob;
      if (part == 0) ccol[pos] = c;
    }
  }
}

// --- layer 1 + segment reduce + fused layer 2 (out): per-node block, 2 waves ---
__global__ __launch_bounds__(128, 4) void layer1out_kernel(
    const float* __restrict__ s2, const short* __restrict__ g2,
    const short* __restrict__ efb, const int* __restrict__ ccol,
    const short* __restrict__ w1eA, const short* __restrict__ w2t,
    const float* __restrict__ b2, const int* __restrict__ row_ptr,
    float* __restrict__ out) {
  __shared__ float hs[128];
  int node = blockIdx.x;
  int tid = threadIdx.x;
  int lane = tid & 63;
  int w = tid >> 6;  // col half 0/1
  int li = lane & 15, lg = lane >> 4;
  int rp = row_ptr[node], rpe = row_ptr[node + 1];
  int deg = rpe - rp;

  if (deg == 0) {
    out[(size_t)node * 128 + tid] = 0.f;   // Hsum=0, deg=0 -> out = 0
    return;                                 // block-uniform branch
  }

  bf16x8 wa[4];
  #pragma unroll
  for (int nt = 0; nt < 4; ++nt)
    wa[nt] = *(const bf16x8*)(w1eA + ((w * 4 + nt) * 64 + lane) * 8);
  f32x4 sreg[4];
  #pragma unroll
  for (int nt = 0; nt < 4; ++nt)
    sreg[nt] = *(const f32x4*)(s2 + (size_t)node * 128 + w * 64 + lg * 16 + nt * 4);
  f32x4 psum[4];
  #pragma unroll
  for (int nt = 0; nt < 4; ++nt) psum[nt] = (f32x4){0.f, 0.f, 0.f, 0.f};

  int ntiles = (deg + 15) >> 4;
  int last = rpe - 1;
  auto ldpos = [&](int t) {
    int p = rp + t * 16 + li;
    return p > last ? last : p;
  };

  // pipeline prologue: tiles 0 and 1 staged; g for tile 0 in flight
  int pA = ldpos(0), pB = ldpos(1);
  int cA = ccol[pA], cB = ccol[pB];
  bf16x8 eA = *(const bf16x8*)(efb + (size_t)pA * ED + lg * 8);
  bf16x8 eB = *(const bf16x8*)(efb + (size_t)pB * ED + lg * 8);
  const short* gpA = g2 + (size_t)cA * 128 + w * 64 + lg * 16;
  bf16x8 gA0 = *(const bf16x8*)gpA;
  bf16x8 gA1 = *(const bf16x8*)(gpA + 8);

  for (int t = 0; t < ntiles; ++t) {
    // prefetch tile t+1's g and tile t+2's pos/col/efb
    const short* gpB = g2 + (size_t)cB * 128 + w * 64 + lg * 16;
    bf16x8 gB0 = *(const bf16x8*)gpB;
    bf16x8 gB1 = *(const bf16x8*)(gpB + 8);
    int pC = ldpos(t + 2);
    int cC = ccol[pC];
    bf16x8 eC = *(const bf16x8*)(efb + (size_t)pC * ED + lg * 8);
    // compute tile t
    f32x4 a0 = __builtin_amdgcn_mfma_f32_16x16x32_bf16(wa[0], eA, (f32x4){0.f,0.f,0.f,0.f}, 0, 0, 0);
    f32x4 a1 = __builtin_amdgcn_mfma_f32_16x16x32_bf16(wa[1], eA, (f32x4){0.f,0.f,0.f,0.f}, 0, 0, 0);
    f32x4 a2 = __builtin_amdgcn_mfma_f32_16x16x32_bf16(wa[2], eA, (f32x4){0.f,0.f,0.f,0.f}, 0, 0, 0);
    f32x4 a3 = __builtin_amdgcn_mfma_f32_16x16x32_bf16(wa[3], eA, (f32x4){0.f,0.f,0.f,0.f}, 0, 0, 0);
    if ((t * 16 + li) < deg) {
      f32x4 v0 = a0 + sreg[0] + bf8lo(gA0);
      f32x4 v1 = a1 + sreg[1] + bf8hi(gA0);
      f32x4 v2 = a2 + sreg[2] + bf8lo(gA1);
      f32x4 v3 = a3 + sreg[3] + bf8hi(gA1);
      #pragma unroll
      for (int r = 0; r < 4; ++r) {
        psum[0][r] += (v0[r] > 0.f ? v0[r] : 0.f);
        psum[1][r] += (v1[r] > 0.f ? v1[r] : 0.f);
        psum[2][r] += (v2[r] > 0.f ? v2[r] : 0.f);
        psum[3][r] += (v3[r] > 0.f ? v3[r] : 0.f);
      }
    }
    // rotate
    cB = cC; eA = eB; eB = eC;
    gA0 = gB0; gA1 = gB1;
  }

  // reduce over the 16 li-lanes (edges); li==0 lanes stage Hsum row in LDS
  #pragma unroll
  for (int nt = 0; nt < 4; ++nt)
    #pragma unroll
    for (int r = 0; r < 4; ++r) {
      float v = psum[nt][r];
      v += __shfl_xor(v, 1);
      v += __shfl_xor(v, 2);
      v += __shfl_xor(v, 4);
      v += __shfl_xor(v, 8);
      psum[nt][r] = v;
    }
  if (li == 0) {
    #pragma unroll
    for (int nt = 0; nt < 4; ++nt)
      *(f32x4*)(hs + w * 64 + nt * 16 + lg * 4) = psum[nt];
  }
  __syncthreads();

  // fused layer 2: out[node][tid] = sum_k hs[k] * W2[k][tid] + deg*b2[tid]
  // w2t row `tid` is W2's column tid (contiguous 128 bf16; whole w2t = 32KB, L1-hot)
  const short* wcol = w2t + tid * 128;
  float acc = 0.f;
  #pragma unroll
  for (int kc = 0; kc < 16; ++kc) {
    bf16x8 wv = *(const bf16x8*)(wcol + kc * 8);
    const float* hp = hs + kc * 8;   // broadcast reads (same addr all lanes)
    #pragma unroll
    for (int j = 0; j < 8; ++j) acc = fmaf(hp[j], bf2f(wv[j]), acc);
  }
  out[(size_t)node * 128 + tid] = acc + (float)deg * b2[tid];
}

extern "C" void kernel_launch(void* const* d_in, const int* in_sizes, int n_in,
                              void* d_out, int out_size, void* d_ws, size_t ws_size,
                              hipStream_t stream) {
  const float* h  = (const float*)d_in[0];
  const void*  ei = d_in[1];
  const float* ef = (const float*)d_in[2];
  const float* W1 = (const float*)d_in[4];
  const float* b1 = (const float*)d_in[5];
  const float* W2 = (const float*)d_in[6];
  const float* b2 = (const float*)d_in[7];
  float* out = (float*)d_out;
  int N = in_sizes[0] / ND;
  int E = in_sizes[2] / ED;

  char* ws = (char*)d_ws;
  size_t off = 0;
  auto alloc = [&](size_t bytes) {
    size_t o = off;
    off = (off + bytes + 255) & ~(size_t)255;
    return o;
  };
  int*          counts  = (int*)(ws + alloc((size_t)N * 4));
  int*          row_ptr = (int*)(ws + alloc((size_t)(N + 1) * 4));
  int*          rank    = (int*)(ws + alloc((size_t)E * 4));
  unsigned int* rc      = (unsigned int*)(ws + alloc((size_t)E * 4));
  short*        w12t    = (short*)(ws + alloc(256 * 128 * 2));
  short*        w1eA    = (short*)(ws + alloc(8 * 64 * 8 * 2));
  short*        w2t     = (short*)(ws + alloc(128 * 128 * 2));
  float*        s2      = (float*)(ws + alloc((size_t)N * 128 * 4));
  short*        g2      = (short*)(ws + alloc((size_t)N * 128 * 2));
  short*        efb     = (short*)(ws + alloc((size_t)E * ED * 2));
  int*          ccol    = (int*)(ws + alloc((size_t)E * 4));

  int SGB = (N + 63) >> 6;
  int SCB = (4 * E + 255) >> 8;

  hipMemsetAsync(counts, 0, (size_t)N * 4, stream);   // MUST precede prep_hist (R11 race)
  prep_hist_kernel<<<128 + (E + 255) / 256, 256, 0, stream>>>(
      W1, W2, ei, counts, rank, rc, w12t, w1eA, w2t, E);
  scan_kernel<<<1, 1024, 0, stream>>>(counts, row_ptr, N);
  scatter_sg_kernel<<<SGB + SCB, 256, 0, stream>>>(
      ef, row_ptr, rank, rc, h, w12t, b1, efb, ccol, s2, g2, N, E);
  layer1out_kernel<<<N, 128, 0, stream>>>(s2, g2, efb, ccol, w1eA, w2t, b2, row_ptr, out);
}

// Round 13
// 139.938 us; speedup vs baseline: 1.1620x; 1.1620x over previous
//
#include <hip/hip_runtime.h>
#include <hip/hip_bf16.h>

// MPNNConv (R10 champion dataflow + embedded-col fp8 edge records):
//   s[n] = h[n] @ W1[0:128] + b1 (f32 swz), g[n] = h[n] @ W1[128:256] (bf16 swz, L2-resident)
//   Hsum[n] = sum_{e: rows[e]=n} relu(s[n] + g[cols[e]] + ef[e] @ W1e)   (K=32 fp8 MFMA)
//   out[n]  = Hsum[n] @ W2 + deg[n]*b2    (separate MFMA out_kernel -- R12's per-node
//                                          VALU GEMV fusion cost +30us, reverted)
// CSR on-device. Edge payload permuted into CSR order as ONE 64B record per edge:
//   {32 x fp8-e4m3 ef | u32 col | pad}  -- written as 4x16B (full line, no RMW),
// eliminating the separate ccol array whose scattered 4B stores amplified to
// ~41MB of line traffic (R10: WRITE 66MB vs 49 ideal). W1e fp8 pre-scaled x16,
// accumulator x1/16 (validated R8, absmax 1.0).
// counts zeroed by hipMemsetAsync BEFORE prep_hist (R11 cross-block race lesson).

typedef __attribute__((ext_vector_type(8))) short bf16x8;
typedef __attribute__((ext_vector_type(4))) float f32x4;

#define ND 128
#define ED 32
#define RECB 64          // bytes per CSR edge record
#define INV_WSCALE 0.0625f

__device__ __forceinline__ short f2bf(float x) {
  unsigned int u = __float_as_uint(x);
  unsigned int r = (u + 0x7FFFu + ((u >> 16) & 1u)) >> 16;
  return (short)r;
}

__device__ __forceinline__ float bf2f(short s) {
  return __uint_as_float(((unsigned int)(unsigned short)s) << 16);
}

__device__ __forceinline__ f32x4 bf8lo(bf16x8 v) {
  f32x4 r;
  #pragma unroll
  for (int j = 0; j < 4; ++j) r[j] = bf2f(v[j]);
  return r;
}
__device__ __forceinline__ f32x4 bf8hi(bf16x8 v) {
  f32x4 r;
  #pragma unroll
  for (int j = 0; j < 4; ++j) r[j] = bf2f(v[4 + j]);
  return r;
}

// pack 4 f32 -> 4 fp8 e4m3 bytes (OCP on gfx950)
__device__ __forceinline__ int pk_fp8x4(float a, float b, float c, float d) {
  int w = __builtin_amdgcn_cvt_pk_fp8_f32(a, b, 0, false);
  w = __builtin_amdgcn_cvt_pk_fp8_f32(c, d, w, true);
  return w;
}

// swizzled offset within a 128-wide row for col c (c = ct*16 + cc)
__device__ __forceinline__ int swz(int c) {
  int ct = c >> 4, cc = c & 15;
  return (ct >> 2) * 64 + (cc >> 2) * 16 + (ct & 3) * 4 + (cc & 3);
}

// --- fused: weight pre-layouts (blocks [0,128)) | hist/rank/rc (rest) ---
__global__ __launch_bounds__(256) void prep_hist_kernel(
    const float* __restrict__ W1, const float* __restrict__ W2,
    const void* __restrict__ ei, int* __restrict__ counts,
    int* __restrict__ rank, unsigned int* __restrict__ rc,
    short* __restrict__ w12t, long long* __restrict__ w1eA8,
    short* __restrict__ w2t, int E) {
  int b = blockIdx.x;
  if (b < 128) {
    int t = b * 256 + threadIdx.x;
    if (t < 256 * 128) {  // w12t[n'][k]: n'<128 -> W1[k][n'] ; else W1[128+k][n'-128]
      int np = t >> 7, k = t & 127;
      float v = (np < 128) ? W1[k * 128 + np] : W1[(128 + k) * 128 + (np - 128)];
      w12t[t] = f2bf(v);
    }
    if (t < 128 * 128) {  // w2t[n][k] = W2[k][n]
      int n = t >> 7, k = t & 127;
      w2t[t] = f2bf(W2[k * 128 + n]);
    }
    if (t < 8 * 64) {     // w1eA8[ct][lane]: 8 fp8 of W1e^T (x16 scale)
      int ct = t >> 6, lane = t & 63;
      int li = lane & 15, lg = lane >> 4;
      float v[8];
      #pragma unroll
      for (int j = 0; j < 8; ++j)
        v[j] = W1[(256 + lg * 8 + j) * 128 + ct * 16 + li] * 16.f;
      int lo = pk_fp8x4(v[0], v[1], v[2], v[3]);
      int hi = pk_fp8x4(v[4], v[5], v[6], v[7]);
      w1eA8[ct * 64 + lane] = (long long)(unsigned int)lo |
                              ((long long)(unsigned int)hi << 32);
    }
  } else {
    int e = (b - 128) * 256 + threadIdx.x;
    if (e < E) {
      const unsigned int* u = (const unsigned int*)ei;
      int is64 = 1;
      #pragma unroll
      for (int i = 0; i < 16; ++i)
        if (u[2 * i + 1] != 0u) is64 = 0;   // uniform addresses -> scalar loads
      int r, c;
      if (is64) {
        r = (int)((const long long*)ei)[e];
        c = (int)((const long long*)ei)[(long long)E + e];
      } else {
        r = ((const int*)ei)[e];
        c = ((const int*)ei)[E + e];
      }
      rank[e] = atomicAdd(&counts[r], 1);
      rc[e] = ((unsigned int)r << 16) | (unsigned int)c;   // N < 65536
    }
  }
}

// --- single-block scan: 1024 threads x 16 elems ---
__global__ __launch_bounds__(1024) void scan_kernel(const int* __restrict__ counts,
                                                    int* __restrict__ row_ptr, int n) {
  __shared__ int wtot[16];
  int tid = threadIdx.x;
  int lane = tid & 63, w = tid >> 6;
  int base_i = tid * 16;
  int c[16];
  int tot = 0;
  #pragma unroll
  for (int j = 0; j < 16; ++j) {
    int i = base_i + j;
    c[j] = (i < n) ? counts[i] : 0;
    tot += c[j];
  }
  int x = tot;
  #pragma unroll
  for (int d = 1; d < 64; d <<= 1) {
    int t = __shfl_up(x, d);
    if (lane >= d) x += t;
  }
  if (lane == 63) wtot[w] = x;
  __syncthreads();
  if (w == 0) {
    int y = (lane < 16) ? wtot[lane] : 0;
    #pragma unroll
    for (int d = 1; d < 16; d <<= 1) {
      int t = __shfl_up(y, d);
      if (lane >= d) y += t;
    }
    if (lane < 16) wtot[lane] = y;
  }
  __syncthreads();
  int waveoff = (w == 0) ? 0 : wtot[w - 1];
  int run = waveoff + x - tot;  // exclusive prefix
  if (tid == 0) row_ptr[0] = 0;
  #pragma unroll
  for (int j = 0; j < 16; ++j) {
    int i = base_i + j;
    if (i < n) {
      run += c[j];
      row_ptr[i + 1] = run;
    }
  }
}

// --- fused: sg GEMM (blocks [0,SGB)) + ef->record fp8 permute (rest) ---
__global__ __launch_bounds__(256, 4) void scatter_sg_kernel(
    const float* __restrict__ ef, const int* __restrict__ row_ptr,
    const int* __restrict__ rank, const unsigned int* __restrict__ rc,
    const float* __restrict__ h, const short* __restrict__ w12t,
    const float* __restrict__ b1, unsigned char* __restrict__ efb,
    float* __restrict__ s2, short* __restrict__ g2, int N, int E) {
  int b = blockIdx.x;
  int SGB = (N + 63) >> 6;
  if (b < SGB) {
    // ---- s = h@W1top + b1 (f32 swz), g = h@W1mid (bf16 swz)
    int lane = threadIdx.x & 63, w = threadIdx.x >> 6;
    int li = lane & 15, lg = lane >> 4;
    int base = b * 64 + w * 16;
    int rowm = base + li;
    if (rowm >= N) rowm = N - 1;
    float breg[8];
    #pragma unroll
    for (int nt = 0; nt < 8; ++nt) breg[nt] = b1[nt * 16 + li];
    f32x4 acc[16];
    #pragma unroll
    for (int nt = 0; nt < 16; ++nt) acc[nt] = (f32x4){0.f, 0.f, 0.f, 0.f};
    #pragma unroll
    for (int kc = 0; kc < 4; ++kc) {
      f32x4 f0 = *(const f32x4*)(h + (size_t)rowm * ND + kc * 32 + lg * 8);
      f32x4 f1 = *(const f32x4*)(h + (size_t)rowm * ND + kc * 32 + lg * 8 + 4);
      bf16x8 a;
      #pragma unroll
      for (int j = 0; j < 4; ++j) { a[j] = f2bf(f0[j]); a[4 + j] = f2bf(f1[j]); }
      #pragma unroll
      for (int nt = 0; nt < 16; ++nt) {
        bf16x8 bb = *(const bf16x8*)(w12t + (nt * 16 + li) * 128 + kc * 32 + lg * 8);
        acc[nt] = __builtin_amdgcn_mfma_f32_16x16x32_bf16(a, bb, acc[nt], 0, 0, 0);
      }
    }
    #pragma unroll
    for (int nt = 0; nt < 16; ++nt)
      #pragma unroll
      for (int r = 0; r < 4; ++r) {
        int row = base + lg * 4 + r;
        if (row < N) {
          if (nt < 8) {
            s2[(size_t)row * 128 + swz(nt * 16 + li)] = acc[nt][r] + breg[nt];
          } else {
            g2[(size_t)row * 128 + swz((nt - 8) * 16 + li)] = f2bf(acc[nt][r]);
          }
        }
      }
  } else {
    // ---- permute: 2 threads/edge; each writes 2x16B -> full 64B line covered
    int gt = (b - SGB) * 256 + threadIdx.x;
    int e = gt >> 1, part = gt & 1;
    if (e < E) {
      unsigned int p = rc[e];
      int r = (int)(p >> 16), c = (int)(p & 0xffffu);
      int pos = row_ptr[r] + rank[e];
      const float* ep = ef + (size_t)e * ED + part * 16;
      f32x4 x0 = *(const f32x4*)(ep);
      f32x4 x1 = *(const f32x4*)(ep + 4);
      f32x4 x2 = *(const f32x4*)(ep + 8);
      f32x4 x3 = *(const f32x4*)(ep + 12);
      int4 ob;
      ob.x = pk_fp8x4(x0[0], x0[1], x0[2], x0[3]);
      ob.y = pk_fp8x4(x1[0], x1[1], x1[2], x1[3]);
      ob.z = pk_fp8x4(x2[0], x2[1], x2[2], x2[3]);
      ob.w = pk_fp8x4(x3[0], x3[1], x3[2], x3[3]);
      unsigned char* rec = efb + (size_t)pos * RECB;
      *(int4*)(rec + part * 16) = ob;                       // fp8 data [0,32)
      *(int4*)(rec + 32 + part * 16) = make_int4(part == 0 ? c : 0, 0, 0, 0);  // meta
    }
  }
}

// --- layer 1 + segment reduce: per-node block, 2 waves (col halves),
//     64B records streamed coalesced (ef fp8 + col same line), g gathered from L2 ---
__global__ __launch_bounds__(128, 4) void layer1_kernel(
    const float* __restrict__ s2, const short* __restrict__ g2,
    const unsigned char* __restrict__ efb, const long long* __restrict__ w1eA8,
    const int* __restrict__ row_ptr, float* __restrict__ hsum) {
  int node = blockIdx.x;
  int lane = threadIdx.x & 63;
  int w = threadIdx.x >> 6;  // col half 0/1
  int li = lane & 15, lg = lane >> 4;
  int rp = row_ptr[node], rpe = row_ptr[node + 1];
  int deg = rpe - rp;

  if (deg == 0) {
    if (li == 0) {
      #pragma unroll
      for (int nt = 0; nt < 4; ++nt)
        *(f32x4*)(hsum + (size_t)node * 128 + w * 64 + nt * 16 + lg * 4) =
            (f32x4){0.f, 0.f, 0.f, 0.f};
    }
    return;
  }

  long long wa[4];
  #pragma unroll
  for (int nt = 0; nt < 4; ++nt)
    wa[nt] = w1eA8[(w * 4 + nt) * 64 + lane];
  f32x4 sreg[4];
  #pragma unroll
  for (int nt = 0; nt < 4; ++nt)
    sreg[nt] = *(const f32x4*)(s2 + (size_t)node * 128 + w * 64 + lg * 16 + nt * 4);
  f32x4 psum[4];
  #pragma unroll
  for (int nt = 0; nt < 4; ++nt) psum[nt] = (f32x4){0.f, 0.f, 0.f, 0.f};

  int ntiles = (deg + 15) >> 4;
  int last = rpe - 1;
  auto ldpos = [&](int t) {
    int p = rp + t * 16 + li;
    return p > last ? last : p;
  };

  // pipeline prologue: records for tiles 0/1; g for tile 0
  const unsigned char* recA = efb + (size_t)ldpos(0) * RECB;
  const unsigned char* recB = efb + (size_t)ldpos(1) * RECB;
  long long eA = *(const long long*)(recA + lg * 8);
  int cA = *(const int*)(recA + 32);
  long long eB = *(const long long*)(recB + lg * 8);
  int cB = *(const int*)(recB + 32);
  const short* gpA = g2 + (size_t)cA * 128 + w * 64 + lg * 16;
  bf16x8 gA0 = *(const bf16x8*)gpA;
  bf16x8 gA1 = *(const bf16x8*)(gpA + 8);

  for (int t = 0; t < ntiles; ++t) {
    // prefetch tile t+1's g and tile t+2's record
    const short* gpB = g2 + (size_t)cB * 128 + w * 64 + lg * 16;
    bf16x8 gB0 = *(const bf16x8*)gpB;
    bf16x8 gB1 = *(const bf16x8*)(gpB + 8);
    const unsigned char* recC = efb + (size_t)ldpos(t + 2) * RECB;
    long long eC = *(const long long*)(recC + lg * 8);
    int cC = *(const int*)(recC + 32);
    // compute tile t (W1e scaled x16 -> acc * 1/16)
    f32x4 a0 = __builtin_amdgcn_mfma_f32_16x16x32_fp8_fp8(wa[0], eA, (f32x4){0.f,0.f,0.f,0.f}, 0, 0, 0);
    f32x4 a1 = __builtin_amdgcn_mfma_f32_16x16x32_fp8_fp8(wa[1], eA, (f32x4){0.f,0.f,0.f,0.f}, 0, 0, 0);
    f32x4 a2 = __builtin_amdgcn_mfma_f32_16x16x32_fp8_fp8(wa[2], eA, (f32x4){0.f,0.f,0.f,0.f}, 0, 0, 0);
    f32x4 a3 = __builtin_amdgcn_mfma_f32_16x16x32_fp8_fp8(wa[3], eA, (f32x4){0.f,0.f,0.f,0.f}, 0, 0, 0);
    if ((t * 16 + li) < deg) {
      f32x4 g0 = bf8lo(gA0), g1 = bf8hi(gA0), g2v = bf8lo(gA1), g3 = bf8hi(gA1);
      #pragma unroll
      for (int r = 0; r < 4; ++r) {
        float v0 = fmaf(a0[r], INV_WSCALE, sreg[0][r] + g0[r]);
        float v1 = fmaf(a1[r], INV_WSCALE, sreg[1][r] + g1[r]);
        float v2 = fmaf(a2[r], INV_WSCALE, sreg[2][r] + g2v[r]);
        float v3 = fmaf(a3[r], INV_WSCALE, sreg[3][r] + g3[r]);
        psum[0][r] += (v0 > 0.f ? v0 : 0.f);
        psum[1][r] += (v1 > 0.f ? v1 : 0.f);
        psum[2][r] += (v2 > 0.f ? v2 : 0.f);
        psum[3][r] += (v3 > 0.f ? v3 : 0.f);
      }
    }
    // rotate
    eA = eB; cB2: ;
    eB = eC;
    cA = cB; cB = cC;
    gA0 = gB0; gA1 = gB1;
  }

  // reduce over the 16 li-lanes (edges), store this wave's col-half
  #pragma unroll
  for (int nt = 0; nt < 4; ++nt)
    #pragma unroll
    for (int r = 0; r < 4; ++r) {
      float v = psum[nt][r];
      v += __shfl_xor(v, 1);
      v += __shfl_xor(v, 2);
      v += __shfl_xor(v, 4);
      v += __shfl_xor(v, 8);
      psum[nt][r] = v;
    }
  if (li == 0) {
    #pragma unroll
    for (int nt = 0; nt < 4; ++nt)
      *(f32x4*)(hsum + (size_t)node * 128 + w * 64 + nt * 16 + lg * 4) = psum[nt];
  }
}

// --- out = Hsum @ W2 + deg*b2 ; 4 waves x 16 rows per block (MFMA) ---
__global__ __launch_bounds__(256) void out_kernel(const float* __restrict__ hsum,
                                                  const short* __restrict__ w2t,
                                                  const float* __restrict__ b2,
                                                  const int* __restrict__ row_ptr,
                                                  float* __restrict__ out, int N) {
  int lane = threadIdx.x & 63, w = threadIdx.x >> 6;
  int li = lane & 15, lg = lane >> 4;
  int base = blockIdx.x * 64 + w * 16;
  int rowm = base + li;
  if (rowm >= N) rowm = N - 1;
  float breg[8];
  #pragma unroll
  for (int nt = 0; nt < 8; ++nt) breg[nt] = b2[nt * 16 + li];
  f32x4 acc[8];
  #pragma unroll
  for (int nt = 0; nt < 8; ++nt) acc[nt] = (f32x4){0.f, 0.f, 0.f, 0.f};
  #pragma unroll
  for (int kc = 0; kc < 4; ++kc) {
    f32x4 f0 = *(const f32x4*)(hsum + (size_t)rowm * 128 + kc * 32 + lg * 8);
    f32x4 f1 = *(const f32x4*)(hsum + (size_t)rowm * 128 + kc * 32 + lg * 8 + 4);
    bf16x8 a;
    #pragma unroll
    for (int j = 0; j < 4; ++j) { a[j] = f2bf(f0[j]); a[4 + j] = f2bf(f1[j]); }
    #pragma unroll
    for (int nt = 0; nt < 8; ++nt) {
      bf16x8 bb = *(const bf16x8*)(w2t + (nt * 16 + li) * 128 + kc * 32 + lg * 8);
      acc[nt] = __builtin_amdgcn_mfma_f32_16x16x32_bf16(a, bb, acc[nt], 0, 0, 0);
    }
  }
  #pragma unroll
  for (int r = 0; r < 4; ++r) {
    int row = base + lg * 4 + r;
    if (row < N) {
      float dg = (float)(row_ptr[row + 1] - row_ptr[row]);
      #pragma unroll
      for (int nt = 0; nt < 8; ++nt)
        out[(size_t)row * 128 + nt * 16 + li] = acc[nt][r] + dg * breg[nt];
    }
  }
}

extern "C" void kernel_launch(void* const* d_in, const int* in_sizes, int n_in,
                              void* d_out, int out_size, void* d_ws, size_t ws_size,
                              hipStream_t stream) {
  const float* h  = (const float*)d_in[0];
  const void*  ei = d_in[1];
  const float* ef = (const float*)d_in[2];
  const float* W1 = (const float*)d_in[4];
  const float* b1 = (const float*)d_in[5];
  const float* W2 = (const float*)d_in[6];
  const float* b2 = (const float*)d_in[7];
  float* out = (float*)d_out;
  int N = in_sizes[0] / ND;
  int E = in_sizes[2] / ED;

  char* ws = (char*)d_ws;
  size_t off = 0;
  auto alloc = [&](size_t bytes) {
    size_t o = off;
    off = (off + bytes + 255) & ~(size_t)255;
    return o;
  };
  int*           counts  = (int*)(ws + alloc((size_t)N * 4));
  int*           row_ptr = (int*)(ws + alloc((size_t)(N + 1) * 4));
  int*           rank    = (int*)(ws + alloc((size_t)E * 4));
  unsigned int*  rc      = (unsigned int*)(ws + alloc((size_t)E * 4));
  short*         w12t    = (short*)(ws + alloc(256 * 128 * 2));
  long long*     w1eA8   = (long long*)(ws + alloc(8 * 64 * 8));
  short*         w2t     = (short*)(ws + alloc(128 * 128 * 2));
  float*         s2      = (float*)(ws + alloc((size_t)N * 128 * 4));
  short*         g2      = (short*)(ws + alloc((size_t)N * 128 * 2));
  float*         hsumb   = (float*)(ws + alloc((size_t)N * 128 * 4));
  unsigned char* efb     = (unsigned char*)(ws + alloc((size_t)E * RECB));

  int SGB = (N + 63) >> 6;
  int SCB = (2 * E + 255) >> 8;

  hipMemsetAsync(counts, 0, (size_t)N * 4, stream);   // MUST precede prep_hist (R11 race)
  prep_hist_kernel<<<128 + (E + 255) / 256, 256, 0, stream>>>(
      W1, W2, ei, counts, rank, rc, w12t, w1eA8, w2t, E);
  scan_kernel<<<1, 1024, 0, stream>>>(counts, row_ptr, N);
  scatter_sg_kernel<<<SGB + SCB, 256, 0, stream>>>(
      ef, row_ptr, rank, rc, h, w12t, b1, efb, s2, g2, N, E);
  layer1_kernel<<<N, 128, 0, stream>>>(s2, g2, efb, w1eA8, row_ptr, hsumb);
  out_kernel<<<(N + 63) / 64, 256, 0, stream>>>(hsumb, w2t, b2, row_ptr, out, N);
}

// Round 14
// 133.654 us; speedup vs baseline: 1.2167x; 1.0470x over previous
//
#include <hip/hip_runtime.h>
#include <hip/hip_bf16.h>

// MPNNConv (R10 champion dataflow; layer1 made persistent/grid-stride):
//   s[n] = h[n] @ W1[0:128] + b1 (f32 swz), g[n] = h[n] @ W1[128:256] (bf16 swz, L2-resident)
//   Hsum[n] = sum_{e: rows[e]=n} relu(s[n] + g[cols[e]] + ef[e] @ W1e)   (K=32 bf16 MFMA)
//   out[n]  = Hsum[n] @ W2 + deg[n]*b2
// CSR on-device; ef permuted into CSR order as bf16 (efb, 64B full-line records)
// + ccol. layer1: 2048 persistent 2-wave blocks grid-striding over nodes
// (R13 diagnosis: 10k short-lived blocks never exceeded 42% occupancy; both big
// kernels are L3-resident and latency-bound, not BW-bound).
// counts zeroed by hipMemsetAsync BEFORE prep_hist (R11 cross-block race).

typedef __attribute__((ext_vector_type(8))) short bf16x8;
typedef __attribute__((ext_vector_type(4))) float f32x4;

#define ND 128
#define ED 32
#define NL1 2048   // persistent layer1 blocks

__device__ __forceinline__ short f2bf(float x) {
  unsigned int u = __float_as_uint(x);
  unsigned int r = (u + 0x7FFFu + ((u >> 16) & 1u)) >> 16;
  return (short)r;
}

__device__ __forceinline__ float bf2f(short s) {
  return __uint_as_float(((unsigned int)(unsigned short)s) << 16);
}

__device__ __forceinline__ f32x4 bf8lo(bf16x8 v) {
  f32x4 r;
  #pragma unroll
  for (int j = 0; j < 4; ++j) r[j] = bf2f(v[j]);
  return r;
}
__device__ __forceinline__ f32x4 bf8hi(bf16x8 v) {
  f32x4 r;
  #pragma unroll
  for (int j = 0; j < 4; ++j) r[j] = bf2f(v[4 + j]);
  return r;
}

// swizzled offset within a 128-wide row for col c (c = ct*16 + cc)
__device__ __forceinline__ int swz(int c) {
  int ct = c >> 4, cc = c & 15;
  return (ct >> 2) * 64 + (cc >> 2) * 16 + (ct & 3) * 4 + (cc & 3);
}

// --- fused: weight pre-layouts (blocks [0,128)) | hist/rank/rc (rest) ---
__global__ __launch_bounds__(256) void prep_hist_kernel(
    const float* __restrict__ W1, const float* __restrict__ W2,
    const void* __restrict__ ei, int* __restrict__ counts,
    int* __restrict__ rank, unsigned int* __restrict__ rc,
    short* __restrict__ w12t, short* __restrict__ w1eA, short* __restrict__ w2t,
    int E) {
  int b = blockIdx.x;
  if (b < 128) {
    int t = b * 256 + threadIdx.x;
    if (t < 256 * 128) {  // w12t[n'][k]: n'<128 -> W1[k][n'] ; else W1[128+k][n'-128]
      int np = t >> 7, k = t & 127;
      float v = (np < 128) ? W1[k * 128 + np] : W1[(128 + k) * 128 + (np - 128)];
      w12t[t] = f2bf(v);
    }
    if (t < 128 * 128) {  // w2t[n][k] = W2[k][n]
      int n = t >> 7, k = t & 127;
      w2t[t] = f2bf(W2[k * 128 + n]);
    }
    if (t < 8 * 64 * 8) { // w1eA[ct][lane][j] = W1[256+lg*8+j][ct*16+li]
      int ct = t >> 9, lane = (t >> 3) & 63, j = t & 7;
      int li = lane & 15, lg = lane >> 4;
      w1eA[t] = f2bf(W1[(256 + lg * 8 + j) * 128 + ct * 16 + li]);
    }
  } else {
    int e = (b - 128) * 256 + threadIdx.x;
    if (e < E) {
      const unsigned int* u = (const unsigned int*)ei;
      int is64 = 1;
      #pragma unroll
      for (int i = 0; i < 16; ++i)
        if (u[2 * i + 1] != 0u) is64 = 0;   // uniform addresses -> scalar loads
      int r, c;
      if (is64) {
        r = (int)((const long long*)ei)[e];
        c = (int)((const long long*)ei)[(long long)E + e];
      } else {
        r = ((const int*)ei)[e];
        c = ((const int*)ei)[E + e];
      }
      rank[e] = atomicAdd(&counts[r], 1);
      rc[e] = ((unsigned int)r << 16) | (unsigned int)c;   // N < 65536
    }
  }
}

// --- single-block scan: 1024 threads x 16 elems ---
__global__ __launch_bounds__(1024) void scan_kernel(const int* __restrict__ counts,
                                                    int* __restrict__ row_ptr, int n) {
  __shared__ int wtot[16];
  int tid = threadIdx.x;
  int lane = tid & 63, w = tid >> 6;
  int base_i = tid * 16;
  int c[16];
  int tot = 0;
  #pragma unroll
  for (int j = 0; j < 16; ++j) {
    int i = base_i + j;
    c[j] = (i < n) ? counts[i] : 0;
    tot += c[j];
  }
  int x = tot;
  #pragma unroll
  for (int d = 1; d < 64; d <<= 1) {
    int t = __shfl_up(x, d);
    if (lane >= d) x += t;
  }
  if (lane == 63) wtot[w] = x;
  __syncthreads();
  if (w == 0) {
    int y = (lane < 16) ? wtot[lane] : 0;
    #pragma unroll
    for (int d = 1; d < 16; d <<= 1) {
      int t = __shfl_up(y, d);
      if (lane >= d) y += t;
    }
    if (lane < 16) wtot[lane] = y;
  }
  __syncthreads();
  int waveoff = (w == 0) ? 0 : wtot[w - 1];
  int run = waveoff + x - tot;  // exclusive prefix
  if (tid == 0) row_ptr[0] = 0;
  #pragma unroll
  for (int j = 0; j < 16; ++j) {
    int i = base_i + j;
    if (i < n) {
      run += c[j];
      row_ptr[i + 1] = run;
    }
  }
}

// --- fused: sg GEMM (blocks [0,SGB)) + ef->efb bf16 permute (rest) ---
__global__ __launch_bounds__(256, 4) void scatter_sg_kernel(
    const float* __restrict__ ef, const int* __restrict__ row_ptr,
    const int* __restrict__ rank, const unsigned int* __restrict__ rc,
    const float* __restrict__ h, const short* __restrict__ w12t,
    const float* __restrict__ b1, short* __restrict__ efb,
    int* __restrict__ ccol, float* __restrict__ s2, short* __restrict__ g2,
    int N, int E) {
  int b = blockIdx.x;
  int SGB = (N + 63) >> 6;
  if (b < SGB) {
    // ---- s = h@W1top + b1 (f32 swz), g = h@W1mid (bf16 swz)
    int lane = threadIdx.x & 63, w = threadIdx.x >> 6;
    int li = lane & 15, lg = lane >> 4;
    int base = b * 64 + w * 16;
    int rowm = base + li;
    if (rowm >= N) rowm = N - 1;
    float breg[8];
    #pragma unroll
    for (int nt = 0; nt < 8; ++nt) breg[nt] = b1[nt * 16 + li];
    f32x4 acc[16];
    #pragma unroll
    for (int nt = 0; nt < 16; ++nt) acc[nt] = (f32x4){0.f, 0.f, 0.f, 0.f};
    #pragma unroll
    for (int kc = 0; kc < 4; ++kc) {
      f32x4 f0 = *(const f32x4*)(h + (size_t)rowm * ND + kc * 32 + lg * 8);
      f32x4 f1 = *(const f32x4*)(h + (size_t)rowm * ND + kc * 32 + lg * 8 + 4);
      bf16x8 a;
      #pragma unroll
      for (int j = 0; j < 4; ++j) { a[j] = f2bf(f0[j]); a[4 + j] = f2bf(f1[j]); }
      #pragma unroll
      for (int nt = 0; nt < 16; ++nt) {
        bf16x8 bb = *(const bf16x8*)(w12t + (nt * 16 + li) * 128 + kc * 32 + lg * 8);
        acc[nt] = __builtin_amdgcn_mfma_f32_16x16x32_bf16(a, bb, acc[nt], 0, 0, 0);
      }
    }
    #pragma unroll
    for (int nt = 0; nt < 16; ++nt)
      #pragma unroll
      for (int r = 0; r < 4; ++r) {
        int row = base + lg * 4 + r;
        if (row < N) {
          if (nt < 8) {
            s2[(size_t)row * 128 + swz(nt * 16 + li)] = acc[nt][r] + breg[nt];
          } else {
            g2[(size_t)row * 128 + swz((nt - 8) * 16 + li)] = f2bf(acc[nt][r]);
          }
        }
      }
  } else {
    // ---- permute: 4 threads/edge; coalesced ef read, full-line scattered write
    int gt = (b - SGB) * 256 + threadIdx.x;
    int e = gt >> 2, part = gt & 3;
    if (e < E) {
      unsigned int p = rc[e];
      int r = (int)(p >> 16), c = (int)(p & 0xffffu);
      int pos = row_ptr[r] + rank[e];
      f32x4 a0 = *(const f32x4*)(ef + (size_t)e * ED + part * 8);
      f32x4 a1 = *(const f32x4*)(ef + (size_t)e * ED + part * 8 + 4);
      bf16x8 ob;
      #pragma unroll
      for (int j = 0; j < 4; ++j) { ob[j] = f2bf(a0[j]); ob[4 + j] = f2bf(a1[j]); }
      *(bf16x8*)(efb + (size_t)pos * ED + part * 8) = ob;
      if (part == 0) ccol[pos] = c;
    }
  }
}

// --- layer 1 + segment reduce: PERSISTENT blocks grid-striding over nodes,
//     2 waves (col halves), efb/ccol streamed, g gathered from L2 ---
__global__ __launch_bounds__(128, 4) void layer1_kernel(
    const float* __restrict__ s2, const short* __restrict__ g2,
    const short* __restrict__ efb, const int* __restrict__ ccol,
    const short* __restrict__ w1eA, const int* __restrict__ row_ptr,
    float* __restrict__ hsum, int N) {
  int lane = threadIdx.x & 63;
  int w = threadIdx.x >> 6;  // col half 0/1
  int li = lane & 15, lg = lane >> 4;

  // weights are node-invariant: load once per block lifetime
  bf16x8 wa[4];
  #pragma unroll
  for (int nt = 0; nt < 4; ++nt)
    wa[nt] = *(const bf16x8*)(w1eA + ((w * 4 + nt) * 64 + lane) * 8);

  for (int node = blockIdx.x; node < N; node += NL1) {
    int rp = row_ptr[node], rpe = row_ptr[node + 1];
    int deg = rpe - rp;

    if (deg == 0) {
      if (li == 0) {
        #pragma unroll
        for (int nt = 0; nt < 4; ++nt)
          *(f32x4*)(hsum + (size_t)node * 128 + w * 64 + nt * 16 + lg * 4) =
              (f32x4){0.f, 0.f, 0.f, 0.f};
      }
      continue;
    }

    f32x4 sreg[4];
    #pragma unroll
    for (int nt = 0; nt < 4; ++nt)
      sreg[nt] = *(const f32x4*)(s2 + (size_t)node * 128 + w * 64 + lg * 16 + nt * 4);
    f32x4 psum[4];
    #pragma unroll
    for (int nt = 0; nt < 4; ++nt) psum[nt] = (f32x4){0.f, 0.f, 0.f, 0.f};

    int ntiles = (deg + 15) >> 4;
    int last = rpe - 1;
    auto ldpos = [&](int t) {
      int p = rp + t * 16 + li;
      return p > last ? last : p;
    };

    // pipeline prologue: tiles 0 and 1 staged; g for tile 0 in flight
    int pA = ldpos(0), pB = ldpos(1);
    int cA = ccol[pA], cB = ccol[pB];
    bf16x8 eA = *(const bf16x8*)(efb + (size_t)pA * ED + lg * 8);
    bf16x8 eB = *(const bf16x8*)(efb + (size_t)pB * ED + lg * 8);
    const short* gpA = g2 + (size_t)cA * 128 + w * 64 + lg * 16;
    bf16x8 gA0 = *(const bf16x8*)gpA;
    bf16x8 gA1 = *(const bf16x8*)(gpA + 8);

    for (int t = 0; t < ntiles; ++t) {
      // prefetch tile t+1's g and tile t+2's pos/col/efb
      const short* gpB = g2 + (size_t)cB * 128 + w * 64 + lg * 16;
      bf16x8 gB0 = *(const bf16x8*)gpB;
      bf16x8 gB1 = *(const bf16x8*)(gpB + 8);
      int pC = ldpos(t + 2);
      int cC = ccol[pC];
      bf16x8 eC = *(const bf16x8*)(efb + (size_t)pC * ED + lg * 8);
      // compute tile t
      f32x4 a0 = __builtin_amdgcn_mfma_f32_16x16x32_bf16(wa[0], eA, (f32x4){0.f,0.f,0.f,0.f}, 0, 0, 0);
      f32x4 a1 = __builtin_amdgcn_mfma_f32_16x16x32_bf16(wa[1], eA, (f32x4){0.f,0.f,0.f,0.f}, 0, 0, 0);
      f32x4 a2 = __builtin_amdgcn_mfma_f32_16x16x32_bf16(wa[2], eA, (f32x4){0.f,0.f,0.f,0.f}, 0, 0, 0);
      f32x4 a3 = __builtin_amdgcn_mfma_f32_16x16x32_bf16(wa[3], eA, (f32x4){0.f,0.f,0.f,0.f}, 0, 0, 0);
      if ((t * 16 + li) < deg) {
        f32x4 v0 = a0 + sreg[0] + bf8lo(gA0);
        f32x4 v1 = a1 + sreg[1] + bf8hi(gA0);
        f32x4 v2 = a2 + sreg[2] + bf8lo(gA1);
        f32x4 v3 = a3 + sreg[3] + bf8hi(gA1);
        #pragma unroll
        for (int r = 0; r < 4; ++r) {
          psum[0][r] += (v0[r] > 0.f ? v0[r] : 0.f);
          psum[1][r] += (v1[r] > 0.f ? v1[r] : 0.f);
          psum[2][r] += (v2[r] > 0.f ? v2[r] : 0.f);
          psum[3][r] += (v3[r] > 0.f ? v3[r] : 0.f);
        }
      }
      // rotate
      cB = cC; eA = eB; eB = eC;
      gA0 = gB0; gA1 = gB1;
    }

    // reduce over the 16 li-lanes (edges), store this wave's col-half
    #pragma unroll
    for (int nt = 0; nt < 4; ++nt)
      #pragma unroll
      for (int r = 0; r < 4; ++r) {
        float v = psum[nt][r];
        v += __shfl_xor(v, 1);
        v += __shfl_xor(v, 2);
        v += __shfl_xor(v, 4);
        v += __shfl_xor(v, 8);
        psum[nt][r] = v;
      }
    if (li == 0) {
      #pragma unroll
      for (int nt = 0; nt < 4; ++nt)
        *(f32x4*)(hsum + (size_t)node * 128 + w * 64 + nt * 16 + lg * 4) = psum[nt];
    }
  }
}

// --- out = Hsum @ W2 + deg*b2 ; 4 waves x 16 rows per block (MFMA) ---
__global__ __launch_bounds__(256) void out_kernel(const float* __restrict__ hsum,
                                                  const short* __restrict__ w2t,
                                                  const float* __restrict__ b2,
                                                  const int* __restrict__ row_ptr,
                                                  float* __restrict__ out, int N) {
  int lane = threadIdx.x & 63, w = threadIdx.x >> 6;
  int li = lane & 15, lg = lane >> 4;
  int base = blockIdx.x * 64 + w * 16;
  int rowm = base + li;
  if (rowm >= N) rowm = N - 1;
  float breg[8];
  #pragma unroll
  for (int nt = 0; nt < 8; ++nt) breg[nt] = b2[nt * 16 + li];
  f32x4 acc[8];
  #pragma unroll
  for (int nt = 0; nt < 8; ++nt) acc[nt] = (f32x4){0.f, 0.f, 0.f, 0.f};
  #pragma unroll
  for (int kc = 0; kc < 4; ++kc) {
    f32x4 f0 = *(const f32x4*)(hsum + (size_t)rowm * 128 + kc * 32 + lg * 8);
    f32x4 f1 = *(const f32x4*)(hsum + (size_t)rowm * 128 + kc * 32 + lg * 8 + 4);
    bf16x8 a;
    #pragma unroll
    for (int j = 0; j < 4; ++j) { a[j] = f2bf(f0[j]); a[4 + j] = f2bf(f1[j]); }
    #pragma unroll
    for (int nt = 0; nt < 8; ++nt) {
      bf16x8 bb = *(const bf16x8*)(w2t + (nt * 16 + li) * 128 + kc * 32 + lg * 8);
      acc[nt] = __builtin_amdgcn_mfma_f32_16x16x32_bf16(a, bb, acc[nt], 0, 0, 0);
    }
  }
  #pragma unroll
  for (int r = 0; r < 4; ++r) {
    int row = base + lg * 4 + r;
    if (row < N) {
      float dg = (float)(row_ptr[row + 1] - row_ptr[row]);
      #pragma unroll
      for (int nt = 0; nt < 8; ++nt)
        out[(size_t)row * 128 + nt * 16 + li] = acc[nt][r] + dg * breg[nt];
    }
  }
}

extern "C" void kernel_launch(void* const* d_in, const int* in_sizes, int n_in,
                              void* d_out, int out_size, void* d_ws, size_t ws_size,
                              hipStream_t stream) {
  const float* h  = (const float*)d_in[0];
  const void*  ei = d_in[1];
  const float* ef = (const float*)d_in[2];
  const float* W1 = (const float*)d_in[4];
  const float* b1 = (const float*)d_in[5];
  const float* W2 = (const float*)d_in[6];
  const float* b2 = (const float*)d_in[7];
  float* out = (float*)d_out;
  int N = in_sizes[0] / ND;
  int E = in_sizes[2] / ED;

  char* ws = (char*)d_ws;
  size_t off = 0;
  auto alloc = [&](size_t bytes) {
    size_t o = off;
    off = (off + bytes + 255) & ~(size_t)255;
    return o;
  };
  int*          counts  = (int*)(ws + alloc((size_t)N * 4));
  int*          row_ptr = (int*)(ws + alloc((size_t)(N + 1) * 4));
  int*          rank    = (int*)(ws + alloc((size_t)E * 4));
  unsigned int* rc      = (unsigned int*)(ws + alloc((size_t)E * 4));
  short*        w12t    = (short*)(ws + alloc(256 * 128 * 2));
  short*        w1eA    = (short*)(ws + alloc(8 * 64 * 8 * 2));
  short*        w2t     = (short*)(ws + alloc(128 * 128 * 2));
  float*        s2      = (float*)(ws + alloc((size_t)N * 128 * 4));
  short*        g2      = (short*)(ws + alloc((size_t)N * 128 * 2));
  float*        hsumb   = (float*)(ws + alloc((size_t)N * 128 * 4));
  short*        efb     = (short*)(ws + alloc((size_t)E * ED * 2));
  int*          ccol    = (int*)(ws + alloc((size_t)E * 4));

  int SGB = (N + 63) >> 6;
  int SCB = (4 * E + 255) >> 8;

  hipMemsetAsync(counts, 0, (size_t)N * 4, stream);   // MUST precede prep_hist (R11 race)
  prep_hist_kernel<<<128 + (E + 255) / 256, 256, 0, stream>>>(
      W1, W2, ei, counts, rank, rc, w12t, w1eA, w2t, E);
  scan_kernel<<<1, 1024, 0, stream>>>(counts, row_ptr, N);
  scatter_sg_kernel<<<SGB + SCB, 256, 0, stream>>>(
      ef, row_ptr, rank, rc, h, w12t, b1, efb, ccol, s2, g2, N, E);
  layer1_kernel<<<NL1, 128, 0, stream>>>(s2, g2, efb, ccol, w1eA, row_ptr, hsumb, N);
  out_kernel<<<(N + 63) / 64, 256, 0, stream>>>(hsumb, w2t, b2, row_ptr, out, N);
}